// Round 1
// baseline (623.287 us; speedup 1.0000x reference)
//
#include <hip/hip_runtime.h>
#include <hip/hip_bf16.h>

// Problem constants
#define NN   10000      // nodes
#define NE   160000     // edges
#define NEP  170000     // edges + self loops
#define IND  20         // input feature dim
#define HIDD 256        // hidden per head
#define NH   4          // heads layer 1
#define HCD  1024       // HEADS*HID
#define LATD 1024

// ---------------- block reduction helpers (shuffle + tiny smem) ----------------
__device__ __forceinline__ float block_reduce_sum1(float v, float* sm) {
    #pragma unroll
    for (int o = 32; o > 0; o >>= 1) v += __shfl_xor(v, o, 64);
    int wid = threadIdx.x >> 6, lane = threadIdx.x & 63, nw = blockDim.x >> 6;
    if (lane == 0) sm[wid] = v;
    __syncthreads();
    float r = 0.f;
    for (int i = 0; i < nw; i++) r += sm[i];
    __syncthreads();
    return r;
}

__device__ __forceinline__ void block_reduce_sum4(float* v, float* sm) {
    #pragma unroll
    for (int h = 0; h < 4; h++) {
        #pragma unroll
        for (int o = 32; o > 0; o >>= 1) v[h] += __shfl_xor(v[h], o, 64);
    }
    int wid = threadIdx.x >> 6, lane = threadIdx.x & 63, nw = blockDim.x >> 6;
    if (lane == 0) {
        sm[wid*4+0] = v[0]; sm[wid*4+1] = v[1]; sm[wid*4+2] = v[2]; sm[wid*4+3] = v[3];
    }
    __syncthreads();
    float r[4] = {0.f, 0.f, 0.f, 0.f};
    for (int i = 0; i < nw; i++) {
        r[0] += sm[i*4+0]; r[1] += sm[i*4+1]; r[2] += sm[i*4+2]; r[3] += sm[i*4+3];
    }
    __syncthreads();
    v[0] = r[0]; v[1] = r[1]; v[2] = r[2]; v[3] = r[3];
}

// ---------------- tiny precompute: collapsed attention matrices ----------------
// prm layout (floats): [0:80)  A_src1[i*4+h]   (20x4)
//                      [80:160) A_dst1[i*4+h]  (20x4)
//                      [160:172) M1[j*4+h]     (3x4)
//                      [172:175) M2[j]         (3)
__global__ void k_prep(const float* __restrict__ W1, const float* __restrict__ as1,
                       const float* __restrict__ ad1, const float* __restrict__ We1,
                       const float* __restrict__ ae1, const float* __restrict__ We2,
                       const float* __restrict__ ae2, float* __restrict__ prm) {
    int t = threadIdx.x;
    if (t < 80) {
        int i = t >> 2, h = t & 3; float s = 0.f;
        for (int c = 0; c < HIDD; c++) s += W1[i*HCD + h*HIDD + c] * as1[h*HIDD + c];
        prm[t] = s;
    } else if (t < 160) {
        int u = t - 80; int i = u >> 2, h = u & 3; float s = 0.f;
        for (int c = 0; c < HIDD; c++) s += W1[i*HCD + h*HIDD + c] * ad1[h*HIDD + c];
        prm[t] = s;
    } else if (t < 172) {
        int u = t - 160; int j = u >> 2, h = u & 3; float s = 0.f;
        for (int c = 0; c < HIDD; c++) s += We1[j*HCD + h*HIDD + c] * ae1[h*HIDD + c];
        prm[t] = s;
    } else if (t < 175) {
        int j = t - 172; float s = 0.f;
        for (int c = 0; c < HIDD; c++) s += We2[j*HIDD + c] * ae2[c];
        prm[t] = s;
    }
}

// ---------------- degree + self-loop edge-attr mean ----------------
__global__ void k_deg(const int* __restrict__ ei, const float* __restrict__ ea,
                      float* __restrict__ cnt, float* __restrict__ lea3) {
    int e = blockIdx.x * 256 + threadIdx.x;
    if (e >= NE) return;
    int d = ei[NE + e];
    atomicAdd(&cnt[d], 1.0f);
    atomicAdd(&lea3[d*3+0], ea[e*3+0]);
    atomicAdd(&lea3[d*3+1], ea[e*3+1]);
    atomicAdd(&lea3[d*3+2], ea[e*3+2]);
}

__global__ void k_loopea(const float* __restrict__ cnt, const float* __restrict__ lea3,
                         float* __restrict__ loop_ea) {
    int v = blockIdx.x * 256 + threadIdx.x;
    if (v >= NN) return;
    float c = fmaxf(cnt[v], 1.0f);
    loop_ea[v*3+0] = lea3[v*3+0] / c;
    loop_ea[v*3+1] = lea3[v*3+1] / c;
    loop_ea[v*3+2] = lea3[v*3+2] / c;
}

// ---------------- exclusive scan of (deg+1) -> CSR offsets ----------------
__global__ void k_scan(const float* __restrict__ cnt, int* __restrict__ offs) {
    __shared__ int sm[1024];
    int t = threadIdx.x;
    int base = t * 10;
    int loc[10]; int s = 0;
    if (t < 1000) {
        #pragma unroll
        for (int i = 0; i < 10; i++) { loc[i] = s; s += (int)cnt[base + i] + 1; }
    }
    sm[t] = (t < 1000) ? s : 0;
    __syncthreads();
    for (int o = 1; o < 1024; o <<= 1) {
        int x = (t >= o) ? sm[t - o] : 0;
        __syncthreads();
        sm[t] += x;
        __syncthreads();
    }
    int pre = (t > 0) ? sm[t - 1] : 0;
    if (t < 1000) {
        #pragma unroll
        for (int i = 0; i < 10; i++) offs[base + i] = pre + loc[i];
    }
    if (t == 1023) offs[NN] = sm[1023];
}

// ---------------- h1 = x @ W1  (store bf16) ----------------
__global__ void k_gemm1(const float* __restrict__ x, const float* __restrict__ W1,
                        __hip_bfloat16* __restrict__ h1) {
    __shared__ float xs[8][IND];
    int t = threadIdx.x;
    int n0 = blockIdx.x * 8;
    int c = blockIdx.y * 256 + t;
    if (t < 8 * IND) xs[t / IND][t % IND] = x[n0 * IND + t];   // contiguous 160 floats
    __syncthreads();
    float acc[8] = {0.f,0.f,0.f,0.f,0.f,0.f,0.f,0.f};
    #pragma unroll
    for (int i = 0; i < IND; i++) {
        float w = W1[i * HCD + c];
        #pragma unroll
        for (int m = 0; m < 8; m++) acc[m] += xs[m][i] * w;
    }
    #pragma unroll
    for (int m = 0; m < 8; m++) h1[(size_t)(n0 + m) * HCD + c] = __float2bfloat16(acc[m]);
}

// ---------------- al_src1/al_dst1 = x @ A (collapsed) ----------------
__global__ void k_al1(const float* __restrict__ x, const float* __restrict__ prm,
                      float* __restrict__ al1) {
    int v = blockIdx.x * 256 + threadIdx.x;
    if (v >= NN) return;
    float xr[IND];
    #pragma unroll
    for (int i = 0; i < IND; i++) xr[i] = x[v * IND + i];
    #pragma unroll
    for (int h = 0; h < NH; h++) {
        float s = 0.f, d = 0.f;
        #pragma unroll
        for (int i = 0; i < IND; i++) { s += xr[i] * prm[i*4 + h]; d += xr[i] * prm[80 + i*4 + h]; }
        al1[v*8 + h] = s;
        al1[v*8 + 4 + h] = d;
    }
}

// ---------------- edge pass layer 1: logits -> exp, CSR fill ----------------
__global__ void k_edge1(const int* __restrict__ ei, const float* __restrict__ ea,
                        const float* __restrict__ loop_ea, const float* __restrict__ al1,
                        const float* __restrict__ prm, const int* __restrict__ offs,
                        int* __restrict__ fill1, int* __restrict__ eslot,
                        int* __restrict__ csrs, float* __restrict__ cex1) {
    int e = blockIdx.x * 256 + threadIdx.x;
    if (e >= NEP) return;
    int s, d; float e0, e1, e2;
    if (e < NE) {
        s = ei[e]; d = ei[NE + e];
        e0 = ea[e*3]; e1 = ea[e*3+1]; e2 = ea[e*3+2];
    } else {
        int v = e - NE; s = v; d = v;
        e0 = loop_ea[v*3]; e1 = loop_ea[v*3+1]; e2 = loop_ea[v*3+2];
    }
    int slot = offs[d] + atomicAdd(&fill1[d], 1);
    eslot[e] = slot;
    csrs[slot] = s;
    float ex[4];
    #pragma unroll
    for (int h = 0; h < NH; h++) {
        float le = e0 * prm[160 + h] + e1 * prm[164 + h] + e2 * prm[168 + h];
        float lg = al1[s*8 + h] + al1[d*8 + 4 + h] + le;
        lg = lg > 0.f ? lg : 0.2f * lg;
        ex[h] = expf(lg);  // no max-shift: logits O(1), mathematically identical post-norm
    }
    *(float4*)(cex1 + (size_t)slot * 4) = make_float4(ex[0], ex[1], ex[2], ex[3]);
}

// ---------------- layer-1 aggregation + bias + ELU + LayerNorm (fused) ----------------
__global__ void __launch_bounds__(256)
k_agg1(const int* __restrict__ offs, const int* __restrict__ csrs,
       const float* __restrict__ cex1, const __hip_bfloat16* __restrict__ h1,
       const float* __restrict__ b1, const float* __restrict__ g1,
       const float* __restrict__ be1, float* __restrict__ h1ln) {
    __shared__ float sm[16];
    int v = blockIdx.x, t = threadIdx.x;
    int beg = offs[v], end = offs[v + 1];
    // softmax denominator per head
    float ps[4] = {0.f,0.f,0.f,0.f};
    for (int j = beg + t; j < end; j += 256) {
        float4 q = *(const float4*)(cex1 + (size_t)j * 4);
        ps[0] += q.x; ps[1] += q.y; ps[2] += q.z; ps[3] += q.w;
    }
    block_reduce_sum4(ps, sm);
    float inv[4];
    #pragma unroll
    for (int h = 0; h < 4; h++) inv[h] = 1.f / (ps[h] + 1e-16f);
    // gather-aggregate
    float acc[4] = {0.f,0.f,0.f,0.f};
    for (int j = beg; j < end; ++j) {
        int s = csrs[j];
        float4 q = *(const float4*)(cex1 + (size_t)j * 4);
        const __hip_bfloat16* hr = h1 + (size_t)s * HCD + t;
        acc[0] += q.x * inv[0] * __bfloat162float(hr[0]);
        acc[1] += q.y * inv[1] * __bfloat162float(hr[256]);
        acc[2] += q.z * inv[2] * __bfloat162float(hr[512]);
        acc[3] += q.w * inv[3] * __bfloat162float(hr[768]);
    }
    // bias + ELU
    float val[4], lsum = 0.f;
    #pragma unroll
    for (int h = 0; h < 4; h++) {
        float xv = acc[h] + b1[h*256 + t];
        xv = xv > 0.f ? xv : expm1f(xv);
        val[h] = xv; lsum += xv;
    }
    // LayerNorm over 1024
    float mu = block_reduce_sum1(lsum, sm) * (1.f / 1024.f);
    float q2 = 0.f;
    #pragma unroll
    for (int h = 0; h < 4; h++) { float dv = val[h] - mu; q2 += dv * dv; }
    float var = block_reduce_sum1(q2, sm) * (1.f / 1024.f);
    float rstd = rsqrtf(var + 1e-5f);
    #pragma unroll
    for (int h = 0; h < 4; h++) {
        int c = h*256 + t;
        h1ln[(size_t)v * HCD + c] = g1[c] * (val[h] - mu) * rstd + be1[c];
    }
}

// ---------------- h2 = h1ln @ W2 (fp32, A rows uniform -> scalar loads) ----------------
__global__ void __launch_bounds__(128)
k_gemm2(const float* __restrict__ A, const float* __restrict__ W2, float* __restrict__ h2) {
    int t = threadIdx.x;
    int n0 = blockIdx.x * 16;
    float acc0[16] = {0.f}, acc1[16] = {0.f};
    for (int k0 = 0; k0 < HCD; k0 += 4) {
        float w0[4], w1[4];
        #pragma unroll
        for (int u = 0; u < 4; u++) {
            w0[u] = W2[(k0 + u) * HIDD + t];
            w1[u] = W2[(k0 + u) * HIDD + t + 128];
        }
        #pragma unroll
        for (int m = 0; m < 16; m++) {
            float4 a = *(const float4*)(A + (size_t)(n0 + m) * HCD + k0);
            acc0[m] += a.x*w0[0] + a.y*w0[1] + a.z*w0[2] + a.w*w0[3];
            acc1[m] += a.x*w1[0] + a.y*w1[1] + a.z*w1[2] + a.w*w1[3];
        }
    }
    #pragma unroll
    for (int m = 0; m < 16; m++) {
        h2[(size_t)(n0 + m) * HIDD + t] = acc0[m];
        h2[(size_t)(n0 + m) * HIDD + t + 128] = acc1[m];
    }
}

// ---------------- al2 = h2 . a_src2 / a_dst2 ----------------
__global__ void k_al2(const float* __restrict__ h2, const float* __restrict__ as2,
                      const float* __restrict__ ad2, float* __restrict__ al2) {
    __shared__ float sm[16];
    int v = blockIdx.x, t = threadIdx.x;
    float hv = h2[(size_t)v * HIDD + t];
    float s = block_reduce_sum1(hv * as2[t], sm);
    float d = block_reduce_sum1(hv * ad2[t], sm);
    if (t == 0) { al2[v*2] = s; al2[v*2+1] = d; }
}

// ---------------- edge pass layer 2 (reuses CSR slots) ----------------
__global__ void k_edge2(const int* __restrict__ ei, const float* __restrict__ ea,
                        const float* __restrict__ loop_ea, const float* __restrict__ al2,
                        const float* __restrict__ prm, const int* __restrict__ eslot,
                        float* __restrict__ cex2) {
    int e = blockIdx.x * 256 + threadIdx.x;
    if (e >= NEP) return;
    int s, d; float e0, e1, e2;
    if (e < NE) {
        s = ei[e]; d = ei[NE + e];
        e0 = ea[e*3]; e1 = ea[e*3+1]; e2 = ea[e*3+2];
    } else {
        int v = e - NE; s = v; d = v;
        e0 = loop_ea[v*3]; e1 = loop_ea[v*3+1]; e2 = loop_ea[v*3+2];
    }
    float lg = al2[s*2] + al2[d*2+1] + e0*prm[172] + e1*prm[173] + e2*prm[174];
    lg = lg > 0.f ? lg : 0.2f * lg;
    cex2[eslot[e]] = expf(lg);
}

// ---------------- layer-2 aggregation + bias + ELU + LN (fused) ----------------
__global__ void __launch_bounds__(256)
k_agg2(const int* __restrict__ offs, const int* __restrict__ csrs,
       const float* __restrict__ cex2, const float* __restrict__ h2,
       const float* __restrict__ b2, const float* __restrict__ g2,
       const float* __restrict__ be2, float* __restrict__ h2ln) {
    __shared__ float sm[16];
    int v = blockIdx.x, t = threadIdx.x;
    int beg = offs[v], end = offs[v + 1];
    float ps = 0.f;
    for (int j = beg + t; j < end; j += 256) ps += cex2[j];
    float ssum = block_reduce_sum1(ps, sm);
    float inv = 1.f / (ssum + 1e-16f);
    float acc = 0.f;
    for (int j = beg; j < end; ++j) {
        acc += cex2[j] * inv * h2[(size_t)csrs[j] * HIDD + t];
    }
    float xv = acc + b2[t];
    xv = xv > 0.f ? xv : expm1f(xv);
    float mu = block_reduce_sum1(xv, sm) * (1.f / 256.f);
    float dv = xv - mu;
    float var = block_reduce_sum1(dv * dv, sm) * (1.f / 256.f);
    float rstd = rsqrtf(var + 1e-5f);
    h2ln[(size_t)v * HIDD + t] = g2[t] * dv * rstd + be2[t];
}

// ---------------- pooling (two-stage, deterministic) ----------------
__global__ void k_pool(const float* __restrict__ h2ln, float* __restrict__ pmean,
                       float* __restrict__ pmax) {
    int b = blockIdx.x, t = threadIdx.x;
    int r0 = b * 250;
    float pm = 0.f, px = -1e30f;
    for (int r = 0; r < 250; r++) {
        float xv = h2ln[(size_t)(r0 + r) * HIDD + t];
        pm += xv; px = fmaxf(px, xv);
    }
    pmean[b*256 + t] = pm;
    pmax[b*256 + t] = px;
}

__global__ void k_pool2(const float* __restrict__ pmean, const float* __restrict__ pmax,
                        float* __restrict__ gvec) {
    int t = threadIdx.x;
    float s = 0.f, m = -1e30f;
    for (int b = 0; b < 40; b++) { s += pmean[b*256 + t]; m = fmaxf(m, pmax[b*256 + t]); }
    gvec[t] = s * (1.f / (float)NN);
    gvec[256 + t] = m;
}

// ---------------- final FC (+relu) and LN ----------------
__global__ void k_fc(const float* __restrict__ gvec, const float* __restrict__ Wfc,
                     const float* __restrict__ bfc, float* __restrict__ fcp) {
    int c = blockIdx.x * 128 + threadIdx.x;
    float acc = bfc[c];
    for (int i = 0; i < 512; i++) acc += gvec[i] * Wfc[i * LATD + c];
    fcp[c] = fmaxf(acc, 0.f);
}

__global__ void k_out(const float* __restrict__ fcp, const float* __restrict__ gf,
                      const float* __restrict__ bf, float* __restrict__ outp) {
    __shared__ float sm[16];
    int t = threadIdx.x;
    float v = fcp[t];
    float mu = block_reduce_sum1(v, sm) * (1.f / 1024.f);
    float dv = v - mu;
    float var = block_reduce_sum1(dv * dv, sm) * (1.f / 1024.f);
    float rstd = rsqrtf(var + 1e-5f);
    outp[t] = gf[t] * dv * rstd + bf[t];
}

// ---------------- launch ----------------
extern "C" void kernel_launch(void* const* d_in, const int* in_sizes, int n_in,
                              void* d_out, int out_size, void* d_ws, size_t ws_size,
                              hipStream_t stream) {
    const float* x      = (const float*)d_in[0];
    const float* ea     = (const float*)d_in[1];
    const float* W1     = (const float*)d_in[2];
    const float* a_src1 = (const float*)d_in[3];
    const float* a_dst1 = (const float*)d_in[4];
    const float* We1    = (const float*)d_in[5];
    const float* a_e1   = (const float*)d_in[6];
    const float* b1     = (const float*)d_in[7];
    const float* g1     = (const float*)d_in[8];
    const float* be1    = (const float*)d_in[9];
    const float* W2     = (const float*)d_in[10];
    const float* a_src2 = (const float*)d_in[11];
    const float* a_dst2 = (const float*)d_in[12];
    const float* We2    = (const float*)d_in[13];
    const float* a_e2   = (const float*)d_in[14];
    const float* b2     = (const float*)d_in[15];
    const float* g2     = (const float*)d_in[16];
    const float* be2    = (const float*)d_in[17];
    const float* Wfc    = (const float*)d_in[18];
    const float* bfc    = (const float*)d_in[19];
    const float* gf     = (const float*)d_in[20];
    const float* bf     = (const float*)d_in[21];
    const int*   ei     = (const int*)d_in[22];
    float* outp = (float*)d_out;

    char* p = (char*)d_ws;
    auto alloc = [&](size_t bytes) -> char* {
        char* r = p;
        p += (bytes + 255) & ~(size_t)255;
        return r;
    };
    // zero zone (one memset): cnt, lea3, fill1
    float* cnt     = (float*)alloc((size_t)NN * 4);
    float* lea3    = (float*)alloc((size_t)NN * 3 * 4);
    int*   fill1   = (int*)  alloc((size_t)NN * 4);
    size_t zbytes  = (size_t)((char*)fill1 + (size_t)NN*4 - (char*)cnt);
    float* loop_ea = (float*)alloc((size_t)NN * 3 * 4);
    float* prm     = (float*)alloc(256 * 4);
    float* al1     = (float*)alloc((size_t)NN * 8 * 4);
    float* al2     = (float*)alloc((size_t)NN * 2 * 4);
    int*   offs    = (int*)  alloc((size_t)(NN + 1) * 4);
    int*   eslot   = (int*)  alloc((size_t)NEP * 4);
    int*   csrs    = (int*)  alloc((size_t)NEP * 4);
    float* cex1    = (float*)alloc((size_t)NEP * 4 * 4);
    float* cex2    = (float*)alloc((size_t)NEP * 4);
    __hip_bfloat16* h1 = (__hip_bfloat16*)alloc((size_t)NN * HCD * 2);
    float* h1ln    = (float*)alloc((size_t)NN * HCD * 4);
    float* h2      = (float*)alloc((size_t)NN * HIDD * 4);
    float* h2ln    = (float*)alloc((size_t)NN * HIDD * 4);
    float* pmean   = (float*)alloc(40 * 256 * 4);
    float* pmax    = (float*)alloc(40 * 256 * 4);
    float* gvec    = (float*)alloc(512 * 4);
    float* fcp     = (float*)alloc(1024 * 4);

    hipMemsetAsync(cnt, 0, zbytes, stream);

    k_prep<<<1, 256, 0, stream>>>(W1, a_src1, a_dst1, We1, a_e1, We2, a_e2, prm);
    k_deg<<<(NE + 255) / 256, 256, 0, stream>>>(ei, ea, cnt, lea3);
    k_loopea<<<(NN + 255) / 256, 256, 0, stream>>>(cnt, lea3, loop_ea);
    k_scan<<<1, 1024, 0, stream>>>(cnt, offs);
    k_gemm1<<<dim3(NN / 8, 4), 256, 0, stream>>>(x, W1, h1);
    k_al1<<<(NN + 255) / 256, 256, 0, stream>>>(x, prm, al1);
    k_edge1<<<(NEP + 255) / 256, 256, 0, stream>>>(ei, ea, loop_ea, al1, prm, offs,
                                                   fill1, eslot, csrs, cex1);
    k_agg1<<<NN, 256, 0, stream>>>(offs, csrs, cex1, h1, b1, g1, be1, h1ln);
    k_gemm2<<<NN / 16, 128, 0, stream>>>(h1ln, W2, h2);
    k_al2<<<NN, 256, 0, stream>>>(h2, a_src2, a_dst2, al2);
    k_edge2<<<(NEP + 255) / 256, 256, 0, stream>>>(ei, ea, loop_ea, al2, prm, eslot, cex2);
    k_agg2<<<NN, 256, 0, stream>>>(offs, csrs, cex2, h2, b2, g2, be2, h2ln);
    k_pool<<<40, 256, 0, stream>>>(h2ln, pmean, pmax);
    k_pool2<<<1, 256, 0, stream>>>(pmean, pmax, gvec);
    k_fc<<<8, 128, 0, stream>>>(gvec, Wfc, bfc, fcp);
    k_out<<<1, 1024, 0, stream>>>(fcp, gf, bf, outp);
}

// Round 2
// 388.634 us; speedup vs baseline: 1.6038x; 1.6038x over previous
//
#include <hip/hip_runtime.h>
#include <hip/hip_bf16.h>

// Problem constants
#define NN   10000      // nodes
#define NE   160000     // edges
#define NEP  170000     // edges + self loops
#define IND  20         // input feature dim
#define HIDD 256        // hidden per head
#define NH   4          // heads layer 1
#define HCD  1024       // HEADS*HID
#define LATD 1024
#define MPAD 10112      // padded rows for h1 bf16 buffers (>= 157*64=10048)

typedef __attribute__((ext_vector_type(8))) short short8v;   // 8 bf16 (4 VGPRs)
typedef __attribute__((ext_vector_type(4))) float f32x4;     // MFMA accumulator

// ---------------- block reduction helpers (shuffle + tiny smem) ----------------
__device__ __forceinline__ float block_reduce_sum1(float v, float* sm) {
    #pragma unroll
    for (int o = 32; o > 0; o >>= 1) v += __shfl_xor(v, o, 64);
    int wid = threadIdx.x >> 6, lane = threadIdx.x & 63, nw = blockDim.x >> 6;
    if (lane == 0) sm[wid] = v;
    __syncthreads();
    float r = 0.f;
    for (int i = 0; i < nw; i++) r += sm[i];
    __syncthreads();
    return r;
}

__device__ __forceinline__ void block_reduce_sum4(float* v, float* sm) {
    #pragma unroll
    for (int h = 0; h < 4; h++) {
        #pragma unroll
        for (int o = 32; o > 0; o >>= 1) v[h] += __shfl_xor(v[h], o, 64);
    }
    int wid = threadIdx.x >> 6, lane = threadIdx.x & 63, nw = blockDim.x >> 6;
    if (lane == 0) {
        sm[wid*4+0] = v[0]; sm[wid*4+1] = v[1]; sm[wid*4+2] = v[2]; sm[wid*4+3] = v[3];
    }
    __syncthreads();
    float r[4] = {0.f, 0.f, 0.f, 0.f};
    for (int i = 0; i < nw; i++) {
        r[0] += sm[i*4+0]; r[1] += sm[i*4+1]; r[2] += sm[i*4+2]; r[3] += sm[i*4+3];
    }
    __syncthreads();
    v[0] = r[0]; v[1] = r[1]; v[2] = r[2]; v[3] = r[3];
}

// ---------------- tiny precompute: collapsed attention matrices ----------------
__global__ void k_prep(const float* __restrict__ W1, const float* __restrict__ as1,
                       const float* __restrict__ ad1, const float* __restrict__ We1,
                       const float* __restrict__ ae1, const float* __restrict__ We2,
                       const float* __restrict__ ae2, float* __restrict__ prm) {
    int t = threadIdx.x;
    if (t < 80) {
        int i = t >> 2, h = t & 3; float s = 0.f;
        for (int c = 0; c < HIDD; c++) s += W1[i*HCD + h*HIDD + c] * as1[h*HIDD + c];
        prm[t] = s;
    } else if (t < 160) {
        int u = t - 80; int i = u >> 2, h = u & 3; float s = 0.f;
        for (int c = 0; c < HIDD; c++) s += W1[i*HCD + h*HIDD + c] * ad1[h*HIDD + c];
        prm[t] = s;
    } else if (t < 172) {
        int u = t - 160; int j = u >> 2, h = u & 3; float s = 0.f;
        for (int c = 0; c < HIDD; c++) s += We1[j*HCD + h*HIDD + c] * ae1[h*HIDD + c];
        prm[t] = s;
    } else if (t < 175) {
        int j = t - 172; float s = 0.f;
        for (int c = 0; c < HIDD; c++) s += We2[j*HIDD + c] * ae2[c];
        prm[t] = s;
    }
}

// ---------------- degree + self-loop edge-attr mean ----------------
__global__ void k_deg(const int* __restrict__ ei, const float* __restrict__ ea,
                      float* __restrict__ cnt, float* __restrict__ lea3) {
    int e = blockIdx.x * 256 + threadIdx.x;
    if (e >= NE) return;
    int d = ei[NE + e];
    atomicAdd(&cnt[d], 1.0f);
    atomicAdd(&lea3[d*3+0], ea[e*3+0]);
    atomicAdd(&lea3[d*3+1], ea[e*3+1]);
    atomicAdd(&lea3[d*3+2], ea[e*3+2]);
}

__global__ void k_loopea(const float* __restrict__ cnt, const float* __restrict__ lea3,
                         float* __restrict__ loop_ea) {
    int v = blockIdx.x * 256 + threadIdx.x;
    if (v >= NN) return;
    float c = fmaxf(cnt[v], 1.0f);
    loop_ea[v*3+0] = lea3[v*3+0] / c;
    loop_ea[v*3+1] = lea3[v*3+1] / c;
    loop_ea[v*3+2] = lea3[v*3+2] / c;
}

// ---------------- exclusive scan of (deg+1) -> CSR offsets ----------------
__global__ void k_scan(const float* __restrict__ cnt, int* __restrict__ offs) {
    __shared__ int sm[1024];
    int t = threadIdx.x;
    int base = t * 10;
    int loc[10]; int s = 0;
    if (t < 1000) {
        #pragma unroll
        for (int i = 0; i < 10; i++) { loc[i] = s; s += (int)cnt[base + i] + 1; }
    }
    sm[t] = (t < 1000) ? s : 0;
    __syncthreads();
    for (int o = 1; o < 1024; o <<= 1) {
        int x = (t >= o) ? sm[t - o] : 0;
        __syncthreads();
        sm[t] += x;
        __syncthreads();
    }
    int pre = (t > 0) ? sm[t - 1] : 0;
    if (t < 1000) {
        #pragma unroll
        for (int i = 0; i < 10; i++) offs[base + i] = pre + loc[i];
    }
    if (t == 1023) offs[NN] = sm[1023];
}

// ---------------- h1 = x @ W1  (store bf16) ----------------
__global__ void k_gemm1(const float* __restrict__ x, const float* __restrict__ W1,
                        __hip_bfloat16* __restrict__ h1) {
    __shared__ float xs[8][IND];
    int t = threadIdx.x;
    int n0 = blockIdx.x * 8;
    int c = blockIdx.y * 256 + t;
    if (t < 8 * IND) xs[t / IND][t % IND] = x[n0 * IND + t];
    __syncthreads();
    float acc[8] = {0.f,0.f,0.f,0.f,0.f,0.f,0.f,0.f};
    #pragma unroll
    for (int i = 0; i < IND; i++) {
        float w = W1[i * HCD + c];
        #pragma unroll
        for (int m = 0; m < 8; m++) acc[m] += xs[m][i] * w;
    }
    #pragma unroll
    for (int m = 0; m < 8; m++) h1[(size_t)(n0 + m) * HCD + c] = __float2bfloat16(acc[m]);
}

// ---------------- al_src1/al_dst1 = x @ A (collapsed) ----------------
__global__ void k_al1(const float* __restrict__ x, const float* __restrict__ prm,
                      float* __restrict__ al1) {
    int v = blockIdx.x * 256 + threadIdx.x;
    if (v >= NN) return;
    float xr[IND];
    #pragma unroll
    for (int i = 0; i < IND; i++) xr[i] = x[v * IND + i];
    #pragma unroll
    for (int h = 0; h < NH; h++) {
        float s = 0.f, d = 0.f;
        #pragma unroll
        for (int i = 0; i < IND; i++) { s += xr[i] * prm[i*4 + h]; d += xr[i] * prm[80 + i*4 + h]; }
        al1[v*8 + h] = s;
        al1[v*8 + 4 + h] = d;
    }
}

// ---------------- edge pass layer 1: logits -> exp, CSR fill ----------------
__global__ void k_edge1(const int* __restrict__ ei, const float* __restrict__ ea,
                        const float* __restrict__ loop_ea, const float* __restrict__ al1,
                        const float* __restrict__ prm, const int* __restrict__ offs,
                        int* __restrict__ fill1, int* __restrict__ eslot,
                        int* __restrict__ csrs, float* __restrict__ cex1) {
    int e = blockIdx.x * 256 + threadIdx.x;
    if (e >= NEP) return;
    int s, d; float e0, e1, e2;
    if (e < NE) {
        s = ei[e]; d = ei[NE + e];
        e0 = ea[e*3]; e1 = ea[e*3+1]; e2 = ea[e*3+2];
    } else {
        int v = e - NE; s = v; d = v;
        e0 = loop_ea[v*3]; e1 = loop_ea[v*3+1]; e2 = loop_ea[v*3+2];
    }
    int slot = offs[d] + atomicAdd(&fill1[d], 1);
    eslot[e] = slot;
    csrs[slot] = s;
    float ex[4];
    #pragma unroll
    for (int h = 0; h < NH; h++) {
        float le = e0 * prm[160 + h] + e1 * prm[164 + h] + e2 * prm[168 + h];
        float lg = al1[s*8 + h] + al1[d*8 + 4 + h] + le;
        lg = lg > 0.f ? lg : 0.2f * lg;
        ex[h] = expf(lg);
    }
    *(float4*)(cex1 + (size_t)slot * 4) = make_float4(ex[0], ex[1], ex[2], ex[3]);
}

// ---------------- layer-1 aggregation + bias + ELU + LayerNorm (fused, bf16 out) ----------------
__global__ void __launch_bounds__(256)
k_agg1(const int* __restrict__ offs, const int* __restrict__ csrs,
       const float* __restrict__ cex1, const __hip_bfloat16* __restrict__ h1,
       const float* __restrict__ b1, const float* __restrict__ g1,
       const float* __restrict__ be1, __hip_bfloat16* __restrict__ h1b) {
    __shared__ float sm[16];
    int v = blockIdx.x, t = threadIdx.x;
    int beg = offs[v], end = offs[v + 1];
    float ps[4] = {0.f,0.f,0.f,0.f};
    for (int j = beg + t; j < end; j += 256) {
        float4 q = *(const float4*)(cex1 + (size_t)j * 4);
        ps[0] += q.x; ps[1] += q.y; ps[2] += q.z; ps[3] += q.w;
    }
    block_reduce_sum4(ps, sm);
    float inv[4];
    #pragma unroll
    for (int h = 0; h < 4; h++) inv[h] = 1.f / (ps[h] + 1e-16f);
    float acc[4] = {0.f,0.f,0.f,0.f};
    for (int j = beg; j < end; ++j) {
        int s = csrs[j];
        float4 q = *(const float4*)(cex1 + (size_t)j * 4);
        const __hip_bfloat16* hr = h1 + (size_t)s * HCD + t;
        acc[0] += q.x * inv[0] * __bfloat162float(hr[0]);
        acc[1] += q.y * inv[1] * __bfloat162float(hr[256]);
        acc[2] += q.z * inv[2] * __bfloat162float(hr[512]);
        acc[3] += q.w * inv[3] * __bfloat162float(hr[768]);
    }
    float val[4], lsum = 0.f;
    #pragma unroll
    for (int h = 0; h < 4; h++) {
        float xv = acc[h] + b1[h*256 + t];
        xv = xv > 0.f ? xv : expm1f(xv);
        val[h] = xv; lsum += xv;
    }
    float mu = block_reduce_sum1(lsum, sm) * (1.f / 1024.f);
    float q2 = 0.f;
    #pragma unroll
    for (int h = 0; h < 4; h++) { float dv = val[h] - mu; q2 += dv * dv; }
    float var = block_reduce_sum1(q2, sm) * (1.f / 1024.f);
    float rstd = rsqrtf(var + 1e-5f);
    #pragma unroll
    for (int h = 0; h < 4; h++) {
        int c = h*256 + t;
        h1b[(size_t)v * HCD + c] = __float2bfloat16(g1[c] * (val[h] - mu) * rstd + be1[c]);
    }
}

// ---------------- W2 -> W2t[256][1024] bf16 (LDS-tiled transpose) ----------------
__global__ void k_w2t(const float* __restrict__ W2, __hip_bfloat16* __restrict__ Bt) {
    __shared__ float sm[64][65];
    int t = threadIdx.x;
    int k0 = blockIdx.x * 64, c0 = blockIdx.y * 64;
    #pragma unroll
    for (int i = 0; i < 16; i++) {
        int idx = i * 256 + t;
        int r = idx >> 6, c = idx & 63;
        sm[r][c] = W2[(size_t)(k0 + r) * 256 + c0 + c];
    }
    __syncthreads();
    int c = t >> 2, kq = t & 3;
    unsigned int out[8];
    #pragma unroll
    for (int j = 0; j < 8; j++) {
        union { __hip_bfloat16 h; unsigned short s; } lo, hi;
        lo.h = __float2bfloat16(sm[kq * 16 + 2*j][c]);
        hi.h = __float2bfloat16(sm[kq * 16 + 2*j + 1][c]);
        out[j] = (unsigned int)lo.s | ((unsigned int)hi.s << 16);
    }
    unsigned int* dst = (unsigned int*)(Bt + (size_t)(c0 + c) * 1024 + k0 + kq * 16);
    *(uint4*)dst = make_uint4(out[0], out[1], out[2], out[3]);
    *(uint4*)(dst + 4) = make_uint4(out[4], out[5], out[6], out[7]);
}

// ---------------- h2 = h1b @ W2t^T via MFMA bf16 ----------------
// Tile: BM=64, BN=64, BK=32. 4 waves: wave w -> (wm=w>>1)*32 rows, (wn=w&1)*32 cols.
// A staged in LDS with XOR swizzle byte ^= ((row&7)<<4) on BOTH write and read.
__global__ void __launch_bounds__(256)
k_gemm2m(const __hip_bfloat16* __restrict__ A, const __hip_bfloat16* __restrict__ Bt,
         float* __restrict__ C) {
    __shared__ uint4 As4[256];           // 64 rows x 32 bf16 = 4 KB
    char* As = (char*)As4;
    int t = threadIdx.x;
    int l = t & 63, w = t >> 6, g = l >> 4;
    int m0 = blockIdx.x * 64, n0 = blockIdx.y * 64;
    // staging: thread t loads 16B; row = t/4, k-chunk = (t%4)*8 elems
    int srow = t >> 2;
    const uint4* gA = (const uint4*)(A + (size_t)(m0 + srow) * 1024 + (t & 3) * 8);
    int swz_w = (t * 16) ^ ((srow & 7) << 4);
    // A-fragment read addressing (two 16-row sub-tiles per wave)
    int wm = w >> 1, wn = w & 1;
    int r0 = wm * 32 + (l & 15);
    int rd0 = ((r0 * 64) + g * 16) ^ ((r0 & 7) << 4);
    int rd1 = (((r0 + 16) * 64) + g * 16) ^ ((r0 & 7) << 4);   // (r0+16)&7 == r0&7
    // B fragments straight from L2-resident W2t
    const short8v* gB0 = (const short8v*)(Bt + (size_t)(n0 + wn * 32 + (l & 15)) * 1024 + g * 8);
    const short8v* gB1 = (const short8v*)((const __hip_bfloat16*)gB0 + (size_t)16 * 1024);
    f32x4 acc00 = {0.f,0.f,0.f,0.f}, acc01 = acc00, acc10 = acc00, acc11 = acc00;
    uint4 sreg = *gA;
    for (int s = 0; s < 32; s++) {
        *(uint4*)(As + swz_w) = sreg;
        __syncthreads();
        if (s < 31) sreg = gA[4 * (s + 1)];          // prefetch next K-step (32 elems = 4 uint4)
        short8v a0 = *(const short8v*)(As + rd0);
        short8v a1 = *(const short8v*)(As + rd1);
        short8v b0 = gB0[4 * s];
        short8v b1 = gB1[4 * s];
        acc00 = __builtin_amdgcn_mfma_f32_16x16x32_bf16(a0, b0, acc00, 0, 0, 0);
        acc01 = __builtin_amdgcn_mfma_f32_16x16x32_bf16(a0, b1, acc01, 0, 0, 0);
        acc10 = __builtin_amdgcn_mfma_f32_16x16x32_bf16(a1, b0, acc10, 0, 0, 0);
        acc11 = __builtin_amdgcn_mfma_f32_16x16x32_bf16(a1, b1, acc11, 0, 0, 0);
        __syncthreads();
    }
    // epilogue: C/D layout col = lane&15, row = (lane>>4)*4 + reg
    int colb = n0 + wn * 32 + (l & 15);
    int rowb0 = m0 + wm * 32 + g * 4;
    #pragma unroll
    for (int r = 0; r < 4; r++) {
        int row = rowb0 + r;
        if (row < NN) {
            C[(size_t)row * HIDD + colb]      = acc00[r];
            C[(size_t)row * HIDD + colb + 16] = acc01[r];
        }
        int row2 = row + 16;
        if (row2 < NN) {
            C[(size_t)row2 * HIDD + colb]      = acc10[r];
            C[(size_t)row2 * HIDD + colb + 16] = acc11[r];
        }
    }
}

// ---------------- al2 = h2 . a_src2 / a_dst2 ----------------
__global__ void k_al2(const float* __restrict__ h2, const float* __restrict__ as2,
                      const float* __restrict__ ad2, float* __restrict__ al2) {
    __shared__ float sm[16];
    int v = blockIdx.x, t = threadIdx.x;
    float hv = h2[(size_t)v * HIDD + t];
    float s = block_reduce_sum1(hv * as2[t], sm);
    float d = block_reduce_sum1(hv * ad2[t], sm);
    if (t == 0) { al2[v*2] = s; al2[v*2+1] = d; }
}

// ---------------- edge pass layer 2 (reuses CSR slots) ----------------
__global__ void k_edge2(const int* __restrict__ ei, const float* __restrict__ ea,
                        const float* __restrict__ loop_ea, const float* __restrict__ al2,
                        const float* __restrict__ prm, const int* __restrict__ eslot,
                        float* __restrict__ cex2) {
    int e = blockIdx.x * 256 + threadIdx.x;
    if (e >= NEP) return;
    int s, d; float e0, e1, e2;
    if (e < NE) {
        s = ei[e]; d = ei[NE + e];
        e0 = ea[e*3]; e1 = ea[e*3+1]; e2 = ea[e*3+2];
    } else {
        int v = e - NE; s = v; d = v;
        e0 = loop_ea[v*3]; e1 = loop_ea[v*3+1]; e2 = loop_ea[v*3+2];
    }
    float lg = al2[s*2] + al2[d*2+1] + e0*prm[172] + e1*prm[173] + e2*prm[174];
    lg = lg > 0.f ? lg : 0.2f * lg;
    cex2[eslot[e]] = expf(lg);
}

// ---------------- layer-2 aggregation + bias + ELU + LN (fused) ----------------
__global__ void __launch_bounds__(256)
k_agg2(const int* __restrict__ offs, const int* __restrict__ csrs,
       const float* __restrict__ cex2, const float* __restrict__ h2,
       const float* __restrict__ b2, const float* __restrict__ g2,
       const float* __restrict__ be2, float* __restrict__ h2ln) {
    __shared__ float sm[16];
    int v = blockIdx.x, t = threadIdx.x;
    int beg = offs[v], end = offs[v + 1];
    float ps = 0.f;
    for (int j = beg + t; j < end; j += 256) ps += cex2[j];
    float ssum = block_reduce_sum1(ps, sm);
    float inv = 1.f / (ssum + 1e-16f);
    float acc = 0.f;
    for (int j = beg; j < end; ++j) {
        acc += cex2[j] * inv * h2[(size_t)csrs[j] * HIDD + t];
    }
    float xv = acc + b2[t];
    xv = xv > 0.f ? xv : expm1f(xv);
    float mu = block_reduce_sum1(xv, sm) * (1.f / 256.f);
    float dv = xv - mu;
    float var = block_reduce_sum1(dv * dv, sm) * (1.f / 256.f);
    float rstd = rsqrtf(var + 1e-5f);
    h2ln[(size_t)v * HIDD + t] = g2[t] * dv * rstd + be2[t];
}

// ---------------- pooling (two-stage, deterministic) ----------------
__global__ void k_pool(const float* __restrict__ h2ln, float* __restrict__ pmean,
                       float* __restrict__ pmax) {
    int b = blockIdx.x, t = threadIdx.x;
    int r0 = b * 250;
    float pm = 0.f, px = -1e30f;
    for (int r = 0; r < 250; r++) {
        float xv = h2ln[(size_t)(r0 + r) * HIDD + t];
        pm += xv; px = fmaxf(px, xv);
    }
    pmean[b*256 + t] = pm;
    pmax[b*256 + t] = px;
}

__global__ void k_pool2(const float* __restrict__ pmean, const float* __restrict__ pmax,
                        float* __restrict__ gvec) {
    int t = threadIdx.x;
    float s = 0.f, m = -1e30f;
    for (int b = 0; b < 40; b++) { s += pmean[b*256 + t]; m = fmaxf(m, pmax[b*256 + t]); }
    gvec[t] = s * (1.f / (float)NN);
    gvec[256 + t] = m;
}

// ---------------- final FC (+relu) and LN ----------------
__global__ void k_fc(const float* __restrict__ gvec, const float* __restrict__ Wfc,
                     const float* __restrict__ bfc, float* __restrict__ fcp) {
    int c = blockIdx.x * 128 + threadIdx.x;
    float acc = bfc[c];
    for (int i = 0; i < 512; i++) acc += gvec[i] * Wfc[i * LATD + c];
    fcp[c] = fmaxf(acc, 0.f);
}

__global__ void k_out(const float* __restrict__ fcp, const float* __restrict__ gf,
                      const float* __restrict__ bf, float* __restrict__ outp) {
    __shared__ float sm[16];
    int t = threadIdx.x;
    float v = fcp[t];
    float mu = block_reduce_sum1(v, sm) * (1.f / 1024.f);
    float dv = v - mu;
    float var = block_reduce_sum1(dv * dv, sm) * (1.f / 1024.f);
    float rstd = rsqrtf(var + 1e-5f);
    outp[t] = gf[t] * dv * rstd + bf[t];
}

// ---------------- launch ----------------
extern "C" void kernel_launch(void* const* d_in, const int* in_sizes, int n_in,
                              void* d_out, int out_size, void* d_ws, size_t ws_size,
                              hipStream_t stream) {
    const float* x      = (const float*)d_in[0];
    const float* ea     = (const float*)d_in[1];
    const float* W1     = (const float*)d_in[2];
    const float* a_src1 = (const float*)d_in[3];
    const float* a_dst1 = (const float*)d_in[4];
    const float* We1    = (const float*)d_in[5];
    const float* a_e1   = (const float*)d_in[6];
    const float* b1     = (const float*)d_in[7];
    const float* g1     = (const float*)d_in[8];
    const float* be1    = (const float*)d_in[9];
    const float* W2     = (const float*)d_in[10];
    const float* a_src2 = (const float*)d_in[11];
    const float* a_dst2 = (const float*)d_in[12];
    const float* We2    = (const float*)d_in[13];
    const float* a_e2   = (const float*)d_in[14];
    const float* b2     = (const float*)d_in[15];
    const float* g2     = (const float*)d_in[16];
    const float* be2    = (const float*)d_in[17];
    const float* Wfc    = (const float*)d_in[18];
    const float* bfc    = (const float*)d_in[19];
    const float* gf     = (const float*)d_in[20];
    const float* bf     = (const float*)d_in[21];
    const int*   ei     = (const int*)d_in[22];
    float* outp = (float*)d_out;

    char* p = (char*)d_ws;
    auto alloc = [&](size_t bytes) -> char* {
        char* r = p;
        p += (bytes + 255) & ~(size_t)255;
        return r;
    };
    // zero zone (one memset): cnt, lea3, fill1
    float* cnt     = (float*)alloc((size_t)NN * 4);
    float* lea3    = (float*)alloc((size_t)NN * 3 * 4);
    int*   fill1   = (int*)  alloc((size_t)NN * 4);
    size_t zbytes  = (size_t)((char*)fill1 + (size_t)NN*4 - (char*)cnt);
    float* loop_ea = (float*)alloc((size_t)NN * 3 * 4);
    float* prm     = (float*)alloc(256 * 4);
    float* al1     = (float*)alloc((size_t)NN * 8 * 4);
    float* al2     = (float*)alloc((size_t)NN * 2 * 4);
    int*   offs    = (int*)  alloc((size_t)(NN + 1) * 4);
    int*   eslot   = (int*)  alloc((size_t)NEP * 4);
    int*   csrs    = (int*)  alloc((size_t)NEP * 4);
    float* cex1    = (float*)alloc((size_t)NEP * 4 * 4);
    float* cex2    = (float*)alloc((size_t)NEP * 4);
    __hip_bfloat16* h1  = (__hip_bfloat16*)alloc((size_t)NN * HCD * 2);
    __hip_bfloat16* h1b = (__hip_bfloat16*)alloc((size_t)MPAD * HCD * 2);  // padded for MFMA tiles
    __hip_bfloat16* w2t = (__hip_bfloat16*)alloc((size_t)HIDD * HCD * 2);
    float* h2      = (float*)alloc((size_t)NN * HIDD * 4);
    float* h2ln    = (float*)alloc((size_t)NN * HIDD * 4);
    float* pmean   = (float*)alloc(40 * 256 * 4);
    float* pmax    = (float*)alloc(40 * 256 * 4);
    float* gvec    = (float*)alloc(512 * 4);
    float* fcp     = (float*)alloc(1024 * 4);

    hipMemsetAsync(cnt, 0, zbytes, stream);

    k_prep<<<1, 256, 0, stream>>>(W1, a_src1, a_dst1, We1, a_e1, We2, a_e2, prm);
    k_w2t<<<dim3(16, 4), 256, 0, stream>>>(W2, w2t);
    k_deg<<<(NE + 255) / 256, 256, 0, stream>>>(ei, ea, cnt, lea3);
    k_loopea<<<(NN + 255) / 256, 256, 0, stream>>>(cnt, lea3, loop_ea);
    k_scan<<<1, 1024, 0, stream>>>(cnt, offs);
    k_gemm1<<<dim3(NN / 8, 4), 256, 0, stream>>>(x, W1, h1);
    k_al1<<<(NN + 255) / 256, 256, 0, stream>>>(x, prm, al1);
    k_edge1<<<(NEP + 255) / 256, 256, 0, stream>>>(ei, ea, loop_ea, al1, prm, offs,
                                                   fill1, eslot, csrs, cex1);
    k_agg1<<<NN, 256, 0, stream>>>(offs, csrs, cex1, h1, b1, g1, be1, h1b);
    k_gemm2m<<<dim3(157, 4), 256, 0, stream>>>(h1b, w2t, h2);
    k_al2<<<NN, 256, 0, stream>>>(h2, a_src2, a_dst2, al2);
    k_edge2<<<(NEP + 255) / 256, 256, 0, stream>>>(ei, ea, loop_ea, al2, prm, eslot, cex2);
    k_agg2<<<NN, 256, 0, stream>>>(offs, csrs, cex2, h2, b2, g2, be2, h2ln);
    k_pool<<<40, 256, 0, stream>>>(h2ln, pmean, pmax);
    k_pool2<<<1, 256, 0, stream>>>(pmean, pmax, gvec);
    k_fc<<<8, 128, 0, stream>>>(gvec, Wfc, bfc, fcp);
    k_out<<<1, 1024, 0, stream>>>(fcp, gf, bf, outp);
}

// Round 3
// 364.460 us; speedup vs baseline: 1.7102x; 1.0663x over previous
//
#include <hip/hip_runtime.h>
#include <hip/hip_bf16.h>

// Problem constants
#define NN   10000      // nodes
#define NE   160000     // edges
#define NEP  170000     // edges + self loops
#define IND  20         // input feature dim
#define HIDD 256        // hidden per head
#define NH   4          // heads layer 1
#define HCD  1024       // HEADS*HID
#define LATD 1024
#define MPAD 10112      // padded rows for h1b (>= 313*32 = 10016)

typedef __attribute__((ext_vector_type(8))) short short8v;   // 8 bf16 (4 VGPRs)
typedef __attribute__((ext_vector_type(4))) float f32x4;     // MFMA accumulator

__device__ __forceinline__ unsigned pk2(float a, float b) {
    union { __hip_bfloat16 h; unsigned short s; } x, y;
    x.h = __float2bfloat16(a); y.h = __float2bfloat16(b);
    return (unsigned)x.s | ((unsigned)y.s << 16);
}

// ---------------- block reduction helper (shuffle + tiny smem) ----------------
__device__ __forceinline__ float block_reduce_sum1(float v, float* sm) {
    #pragma unroll
    for (int o = 32; o > 0; o >>= 1) v += __shfl_xor(v, o, 64);
    int wid = threadIdx.x >> 6, lane = threadIdx.x & 63, nw = blockDim.x >> 6;
    if (lane == 0) sm[wid] = v;
    __syncthreads();
    float r = 0.f;
    for (int i = 0; i < nw; i++) r += sm[i];
    __syncthreads();
    return r;
}

// ---------------- tiny precompute: collapsed attention matrices ----------------
__global__ void k_prep(const float* __restrict__ W1, const float* __restrict__ as1,
                       const float* __restrict__ ad1, const float* __restrict__ We1,
                       const float* __restrict__ ae1, const float* __restrict__ We2,
                       const float* __restrict__ ae2, float* __restrict__ prm) {
    int t = threadIdx.x;
    if (t < 80) {
        int i = t >> 2, h = t & 3; float s = 0.f;
        for (int c = 0; c < HIDD; c++) s += W1[i*HCD + h*HIDD + c] * as1[h*HIDD + c];
        prm[t] = s;
    } else if (t < 160) {
        int u = t - 80; int i = u >> 2, h = u & 3; float s = 0.f;
        for (int c = 0; c < HIDD; c++) s += W1[i*HCD + h*HIDD + c] * ad1[h*HIDD + c];
        prm[t] = s;
    } else if (t < 172) {
        int u = t - 160; int j = u >> 2, h = u & 3; float s = 0.f;
        for (int c = 0; c < HIDD; c++) s += We1[j*HCD + h*HIDD + c] * ae1[h*HIDD + c];
        prm[t] = s;
    } else if (t < 175) {
        int j = t - 172; float s = 0.f;
        for (int c = 0; c < HIDD; c++) s += We2[j*HIDD + c] * ae2[c];
        prm[t] = s;
    }
}

// ---------------- degree + self-loop edge-attr mean ----------------
__global__ void k_deg(const int* __restrict__ ei, const float* __restrict__ ea,
                      float* __restrict__ cnt, float* __restrict__ lea3) {
    int e = blockIdx.x * 256 + threadIdx.x;
    if (e >= NE) return;
    int d = ei[NE + e];
    atomicAdd(&cnt[d], 1.0f);
    atomicAdd(&lea3[d*3+0], ea[e*3+0]);
    atomicAdd(&lea3[d*3+1], ea[e*3+1]);
    atomicAdd(&lea3[d*3+2], ea[e*3+2]);
}

__global__ void k_loopea(const float* __restrict__ cnt, const float* __restrict__ lea3,
                         float* __restrict__ loop_ea) {
    int v = blockIdx.x * 256 + threadIdx.x;
    if (v >= NN) return;
    float c = fmaxf(cnt[v], 1.0f);
    loop_ea[v*3+0] = lea3[v*3+0] / c;
    loop_ea[v*3+1] = lea3[v*3+1] / c;
    loop_ea[v*3+2] = lea3[v*3+2] / c;
}

// ---------------- exclusive scan of (deg+1) -> CSR offsets ----------------
__global__ void k_scan(const float* __restrict__ cnt, int* __restrict__ offs) {
    __shared__ int sm[1024];
    int t = threadIdx.x;
    int base = t * 10;
    int loc[10]; int s = 0;
    if (t < 1000) {
        #pragma unroll
        for (int i = 0; i < 10; i++) { loc[i] = s; s += (int)cnt[base + i] + 1; }
    }
    sm[t] = (t < 1000) ? s : 0;
    __syncthreads();
    for (int o = 1; o < 1024; o <<= 1) {
        int x = (t >= o) ? sm[t - o] : 0;
        __syncthreads();
        sm[t] += x;
        __syncthreads();
    }
    int pre = (t > 0) ? sm[t - 1] : 0;
    if (t < 1000) {
        #pragma unroll
        for (int i = 0; i < 10; i++) offs[base + i] = pre + loc[i];
    }
    if (t == 1023) offs[NN] = sm[1023];
}

// ---------------- h1 = x @ W1  (store bf16) ----------------
__global__ void k_gemm1(const float* __restrict__ x, const float* __restrict__ W1,
                        __hip_bfloat16* __restrict__ h1) {
    __shared__ float xs[8][IND];
    int t = threadIdx.x;
    int n0 = blockIdx.x * 8;
    int c = blockIdx.y * 256 + t;
    if (t < 8 * IND) xs[t / IND][t % IND] = x[n0 * IND + t];
    __syncthreads();
    float acc[8] = {0.f,0.f,0.f,0.f,0.f,0.f,0.f,0.f};
    #pragma unroll
    for (int i = 0; i < IND; i++) {
        float w = W1[i * HCD + c];
        #pragma unroll
        for (int m = 0; m < 8; m++) acc[m] += xs[m][i] * w;
    }
    #pragma unroll
    for (int m = 0; m < 8; m++) h1[(size_t)(n0 + m) * HCD + c] = __float2bfloat16(acc[m]);
}

// ---------------- al_src1/al_dst1 = x @ A (collapsed) ----------------
__global__ void k_al1(const float* __restrict__ x, const float* __restrict__ prm,
                      float* __restrict__ al1) {
    int v = blockIdx.x * 256 + threadIdx.x;
    if (v >= NN) return;
    float xr[IND];
    #pragma unroll
    for (int i = 0; i < IND; i++) xr[i] = x[v * IND + i];
    #pragma unroll
    for (int h = 0; h < NH; h++) {
        float s = 0.f, d = 0.f;
        #pragma unroll
        for (int i = 0; i < IND; i++) { s += xr[i] * prm[i*4 + h]; d += xr[i] * prm[80 + i*4 + h]; }
        al1[v*8 + h] = s;
        al1[v*8 + 4 + h] = d;
    }
}

// ---------------- edge pass layer 1: logits -> exp, CSR fill ----------------
__global__ void k_edge1(const int* __restrict__ ei, const float* __restrict__ ea,
                        const float* __restrict__ loop_ea, const float* __restrict__ al1,
                        const float* __restrict__ prm, const int* __restrict__ offs,
                        int* __restrict__ fill1, int* __restrict__ eslot,
                        int* __restrict__ csrs, float* __restrict__ cex1) {
    int e = blockIdx.x * 256 + threadIdx.x;
    if (e >= NEP) return;
    int s, d; float e0, e1, e2;
    if (e < NE) {
        s = ei[e]; d = ei[NE + e];
        e0 = ea[e*3]; e1 = ea[e*3+1]; e2 = ea[e*3+2];
    } else {
        int v = e - NE; s = v; d = v;
        e0 = loop_ea[v*3]; e1 = loop_ea[v*3+1]; e2 = loop_ea[v*3+2];
    }
    int slot = offs[d] + atomicAdd(&fill1[d], 1);
    eslot[e] = slot;
    csrs[slot] = s;
    float ex[4];
    #pragma unroll
    for (int h = 0; h < NH; h++) {
        float le = e0 * prm[160 + h] + e1 * prm[164 + h] + e2 * prm[168 + h];
        float lg = al1[s*8 + h] + al1[d*8 + 4 + h] + le;
        lg = lg > 0.f ? lg : 0.2f * lg;
        ex[h] = expf(lg);
    }
    *(float4*)(cex1 + (size_t)slot * 4) = make_float4(ex[0], ex[1], ex[2], ex[3]);
}

// ---------------- layer-1 aggregation + bias + ELU + LN, wave-per-node ----------------
// Lane l owns features 16l..16l+15 (32 B of the bf16 row). Head = l>>4.
#define UNPK(U, A0, A1) { unsigned _u = (U); A0 += a * __uint_as_float(_u << 16); A1 += a * __uint_as_float(_u & 0xffff0000u); }
__global__ void __launch_bounds__(256)
k_agg1(const int* __restrict__ offs, const int* __restrict__ csrs,
       const float* __restrict__ cex1, const __hip_bfloat16* __restrict__ h1,
       const float* __restrict__ b1, const float* __restrict__ g1,
       const float* __restrict__ be1, __hip_bfloat16* __restrict__ h1b) {
    int l = threadIdx.x & 63;
    int v = blockIdx.x * 4 + (threadIdx.x >> 6);
    int beg = offs[v], end = offs[v + 1];
    // pass 1: softmax denominator. lanes cover 16 edges x 4 components per step.
    float ps = 0.f;
    for (int j = beg + (l >> 2); j < end; j += 16)
        ps += cex1[(size_t)j * 4 + (l & 3)];
    #pragma unroll
    for (int o = 4; o <= 32; o <<= 1) ps += __shfl_xor(ps, o, 64);
    float inv = 1.f / (__shfl(ps, l >> 4) + 1e-16f);   // lane c holds component c total
    // pass 2: gather-aggregate, 32 B per lane per edge
    float c0=0,c1=0,c2=0,c3=0,c4=0,c5=0,c6=0,c7=0,c8=0,c9=0,c10=0,c11=0,c12=0,c13=0,c14=0,c15=0;
    const uint4* hU = (const uint4*)h1;
    for (int j = beg; j < end; ++j) {
        int s = csrs[j];                                   // broadcast
        float a = cex1[(size_t)j * 4 + (l >> 4)] * inv;    // 4-word broadcast
        uint4 p0 = hU[(size_t)s * 128 + l * 2];
        uint4 p1 = hU[(size_t)s * 128 + l * 2 + 1];
        UNPK(p0.x, c0, c1);  UNPK(p0.y, c2, c3);  UNPK(p0.z, c4, c5);  UNPK(p0.w, c6, c7);
        UNPK(p1.x, c8, c9);  UNPK(p1.y, c10,c11); UNPK(p1.z, c12,c13); UNPK(p1.w, c14,c15);
    }
    float vv[16] = {c0,c1,c2,c3,c4,c5,c6,c7,c8,c9,c10,c11,c12,c13,c14,c15};
    // bias + ELU
    const float4* b4 = (const float4*)(b1 + 16 * l);
    float lsum = 0.f;
    #pragma unroll
    for (int q = 0; q < 4; q++) {
        float4 bb = b4[q];
        float xv;
        xv = vv[4*q+0] + bb.x; xv = xv > 0.f ? xv : expm1f(xv); vv[4*q+0] = xv; lsum += xv;
        xv = vv[4*q+1] + bb.y; xv = xv > 0.f ? xv : expm1f(xv); vv[4*q+1] = xv; lsum += xv;
        xv = vv[4*q+2] + bb.z; xv = xv > 0.f ? xv : expm1f(xv); vv[4*q+2] = xv; lsum += xv;
        xv = vv[4*q+3] + bb.w; xv = xv > 0.f ? xv : expm1f(xv); vv[4*q+3] = xv; lsum += xv;
    }
    // LayerNorm over 1024 via wave butterfly
    #pragma unroll
    for (int o = 1; o <= 32; o <<= 1) lsum += __shfl_xor(lsum, o, 64);
    float mu = lsum * (1.f / 1024.f);
    float q2 = 0.f;
    #pragma unroll
    for (int i = 0; i < 16; i++) { float dv = vv[i] - mu; q2 += dv * dv; }
    #pragma unroll
    for (int o = 1; o <= 32; o <<= 1) q2 += __shfl_xor(q2, o, 64);
    float rstd = rsqrtf(q2 * (1.f / 1024.f) + 1e-5f);
    const float4* g4 = (const float4*)(g1 + 16 * l);
    const float4* e4 = (const float4*)(be1 + 16 * l);
    unsigned ou[8];
    #pragma unroll
    for (int q = 0; q < 4; q++) {
        float4 gg = g4[q], ee = e4[q];
        float y0 = gg.x * (vv[4*q+0] - mu) * rstd + ee.x;
        float y1 = gg.y * (vv[4*q+1] - mu) * rstd + ee.y;
        float y2 = gg.z * (vv[4*q+2] - mu) * rstd + ee.z;
        float y3 = gg.w * (vv[4*q+3] - mu) * rstd + ee.w;
        ou[2*q]   = pk2(y0, y1);
        ou[2*q+1] = pk2(y2, y3);
    }
    uint4* dst = (uint4*)(h1b + (size_t)v * HCD + 16 * l);
    dst[0] = make_uint4(ou[0], ou[1], ou[2], ou[3]);
    dst[1] = make_uint4(ou[4], ou[5], ou[6], ou[7]);
}

// ---------------- W2 -> W2t[256][1024] bf16 (LDS-tiled transpose) ----------------
__global__ void k_w2t(const float* __restrict__ W2, __hip_bfloat16* __restrict__ Bt) {
    __shared__ float sm[64][65];
    int t = threadIdx.x;
    int k0 = blockIdx.x * 64, c0 = blockIdx.y * 64;
    #pragma unroll
    for (int i = 0; i < 16; i++) {
        int idx = i * 256 + t;
        int r = idx >> 6, c = idx & 63;
        sm[r][c] = W2[(size_t)(k0 + r) * 256 + c0 + c];
    }
    __syncthreads();
    int c = t >> 2, kq = t & 3;
    unsigned int out[8];
    #pragma unroll
    for (int j = 0; j < 8; j++)
        out[j] = pk2(sm[kq * 16 + 2*j][c], sm[kq * 16 + 2*j + 1][c]);
    unsigned int* dst = (unsigned int*)(Bt + (size_t)(c0 + c) * 1024 + k0 + kq * 16);
    *(uint4*)dst = make_uint4(out[0], out[1], out[2], out[3]);
    *(uint4*)(dst + 4) = make_uint4(out[4], out[5], out[6], out[7]);
}

// ---------------- h2b = h1b @ W2t^T via MFMA bf16; BM=32, BN=256 (A read once) ----------------
__global__ void __launch_bounds__(256)
k_gemm2m(const __hip_bfloat16* __restrict__ A, const __hip_bfloat16* __restrict__ Bt,
         __hip_bfloat16* __restrict__ h2b) {
    __shared__ uint4 As4[256];   // 32 rows x 64 bf16 = 4 KB, XOR-swizzled
    char* As = (char*)As4;
    int t = threadIdx.x, l = t & 63, w = t >> 6;
    int m0 = blockIdx.x * 32;
    int srow = t >> 3, skc = t & 7;
    const __hip_bfloat16* gA = A + (size_t)(m0 + srow) * 1024 + skc * 8;
    int wbyte = (srow * 128 + skc * 16) ^ ((srow & 7) << 4);
    int r0 = l & 15, g = l >> 4;
    // A-frag swizzled byte offsets (m in {0,1}, kk in {0,1})
    int ra[2][2];
    #pragma unroll
    for (int m = 0; m < 2; m++)
        #pragma unroll
        for (int kk = 0; kk < 2; kk++) {
            int r = r0 + m * 16;
            ra[m][kk] = (r * 128 + kk * 64 + g * 16) ^ ((r & 7) << 4);
        }
    const __hip_bfloat16* gB = Bt + (size_t)(w * 64 + r0) * 1024 + g * 8;
    f32x4 acc[2][4];
    #pragma unroll
    for (int m = 0; m < 2; m++)
        #pragma unroll
        for (int n = 0; n < 4; n++) acc[m][n] = (f32x4){0.f,0.f,0.f,0.f};
    uint4 sreg = *(const uint4*)gA;
    for (int it = 0; it < 16; ++it) {
        *(uint4*)(As + wbyte) = sreg;
        __syncthreads();
        if (it < 15) sreg = *(const uint4*)(gA + (it + 1) * 64);
        int k0 = it * 64;
        short8v bfr[4][2];
        #pragma unroll
        for (int n = 0; n < 4; n++)
            #pragma unroll
            for (int kk = 0; kk < 2; kk++)
                bfr[n][kk] = *(const short8v*)(gB + (size_t)n * 16 * 1024 + k0 + kk * 32);
        short8v afr[2][2];
        #pragma unroll
        for (int m = 0; m < 2; m++)
            #pragma unroll
            for (int kk = 0; kk < 2; kk++)
                afr[m][kk] = *(const short8v*)(As + ra[m][kk]);
        #pragma unroll
        for (int kk = 0; kk < 2; kk++)
            #pragma unroll
            for (int m = 0; m < 2; m++)
                #pragma unroll
                for (int n = 0; n < 4; n++)
                    acc[m][n] = __builtin_amdgcn_mfma_f32_16x16x32_bf16(afr[m][kk], bfr[n][kk], acc[m][n], 0, 0, 0);
        __syncthreads();
    }
    // epilogue: row = (lane>>4)*4 + reg, col = lane&15; store bf16
    #pragma unroll
    for (int m = 0; m < 2; m++) {
        #pragma unroll
        for (int r = 0; r < 4; r++) {
            int row = m0 + m * 16 + g * 4 + r;
            if (row < NN) {
                #pragma unroll
                for (int n = 0; n < 4; n++) {
                    int col = w * 64 + n * 16 + r0;
                    h2b[(size_t)row * HIDD + col] = __float2bfloat16(acc[m][n][r]);
                }
            }
        }
    }
}

// ---------------- al2 = h2b . a_src2 / a_dst2, wave-per-node ----------------
__global__ void __launch_bounds__(256)
k_al2(const __hip_bfloat16* __restrict__ h2b, const float* __restrict__ as2,
      const float* __restrict__ ad2, float* __restrict__ al2) {
    int l = threadIdx.x & 63;
    int v = blockIdx.x * 4 + (threadIdx.x >> 6);
    uint2 p = ((const uint2*)h2b)[(size_t)v * 64 + l];
    float f0 = __uint_as_float(p.x << 16), f1 = __uint_as_float(p.x & 0xffff0000u);
    float f2 = __uint_as_float(p.y << 16), f3 = __uint_as_float(p.y & 0xffff0000u);
    float4 sa = ((const float4*)as2)[l];
    float4 da = ((const float4*)ad2)[l];
    float s = f0*sa.x + f1*sa.y + f2*sa.z + f3*sa.w;
    float d = f0*da.x + f1*da.y + f2*da.z + f3*da.w;
    #pragma unroll
    for (int o = 1; o <= 32; o <<= 1) { s += __shfl_xor(s, o, 64); d += __shfl_xor(d, o, 64); }
    if (l == 0) { al2[v*2] = s; al2[v*2+1] = d; }
}

// ---------------- edge pass layer 2 (reuses CSR slots) ----------------
__global__ void k_edge2(const int* __restrict__ ei, const float* __restrict__ ea,
                        const float* __restrict__ loop_ea, const float* __restrict__ al2,
                        const float* __restrict__ prm, const int* __restrict__ eslot,
                        float* __restrict__ cex2) {
    int e = blockIdx.x * 256 + threadIdx.x;
    if (e >= NEP) return;
    int s, d; float e0, e1, e2;
    if (e < NE) {
        s = ei[e]; d = ei[NE + e];
        e0 = ea[e*3]; e1 = ea[e*3+1]; e2 = ea[e*3+2];
    } else {
        int v = e - NE; s = v; d = v;
        e0 = loop_ea[v*3]; e1 = loop_ea[v*3+1]; e2 = loop_ea[v*3+2];
    }
    float lg = al2[s*2] + al2[d*2+1] + e0*prm[172] + e1*prm[173] + e2*prm[174];
    lg = lg > 0.f ? lg : 0.2f * lg;
    cex2[eslot[e]] = expf(lg);
}

// ---------------- layer-2 aggregation + bias + ELU + LN, wave-per-node ----------------
__global__ void __launch_bounds__(256)
k_agg2(const int* __restrict__ offs, const int* __restrict__ csrs,
       const float* __restrict__ cex2, const __hip_bfloat16* __restrict__ h2b,
       const float* __restrict__ b2, const float* __restrict__ g2,
       const float* __restrict__ be2, float* __restrict__ h2ln) {
    int l = threadIdx.x & 63;
    int v = blockIdx.x * 4 + (threadIdx.x >> 6);
    int beg = offs[v], end = offs[v + 1];
    float ps = 0.f;
    for (int j = beg + l; j < end; j += 64) ps += cex2[j];
    #pragma unroll
    for (int o = 1; o <= 32; o <<= 1) ps += __shfl_xor(ps, o, 64);
    float inv = 1.f / (ps + 1e-16f);
    float a0 = 0.f, a1 = 0.f, a2 = 0.f, a3 = 0.f;
    const uint2* hU = (const uint2*)h2b;
    for (int j = beg; j < end; ++j) {
        int s = csrs[j];                       // broadcast
        float aw = cex2[j] * inv;              // broadcast
        uint2 p = hU[(size_t)s * 64 + l];
        a0 += aw * __uint_as_float(p.x << 16);
        a1 += aw * __uint_as_float(p.x & 0xffff0000u);
        a2 += aw * __uint_as_float(p.y << 16);
        a3 += aw * __uint_as_float(p.y & 0xffff0000u);
    }
    float4 bb = ((const float4*)b2)[l];
    float v0 = a0 + bb.x, v1 = a1 + bb.y, v2 = a2 + bb.z, v3 = a3 + bb.w;
    v0 = v0 > 0.f ? v0 : expm1f(v0);
    v1 = v1 > 0.f ? v1 : expm1f(v1);
    v2 = v2 > 0.f ? v2 : expm1f(v2);
    v3 = v3 > 0.f ? v3 : expm1f(v3);
    float lsum = v0 + v1 + v2 + v3;
    #pragma unroll
    for (int o = 1; o <= 32; o <<= 1) lsum += __shfl_xor(lsum, o, 64);
    float mu = lsum * (1.f / 256.f);
    float q2 = (v0-mu)*(v0-mu) + (v1-mu)*(v1-mu) + (v2-mu)*(v2-mu) + (v3-mu)*(v3-mu);
    #pragma unroll
    for (int o = 1; o <= 32; o <<= 1) q2 += __shfl_xor(q2, o, 64);
    float rstd = rsqrtf(q2 * (1.f / 256.f) + 1e-5f);
    float4 gg = ((const float4*)g2)[l];
    float4 ee = ((const float4*)be2)[l];
    float4 outv;
    outv.x = gg.x * (v0 - mu) * rstd + ee.x;
    outv.y = gg.y * (v1 - mu) * rstd + ee.y;
    outv.z = gg.z * (v2 - mu) * rstd + ee.z;
    outv.w = gg.w * (v3 - mu) * rstd + ee.w;
    ((float4*)h2ln)[(size_t)v * 64 + l] = outv;
}

// ---------------- pooling (two-stage, deterministic) ----------------
__global__ void k_pool(const float* __restrict__ h2ln, float* __restrict__ pmean,
                       float* __restrict__ pmax) {
    int b = blockIdx.x, t = threadIdx.x;
    int r0 = b * 250;
    float pm = 0.f, px = -1e30f;
    for (int r = 0; r < 250; r++) {
        float xv = h2ln[(size_t)(r0 + r) * HIDD + t];
        pm += xv; px = fmaxf(px, xv);
    }
    pmean[b*256 + t] = pm;
    pmax[b*256 + t] = px;
}

__global__ void k_pool2(const float* __restrict__ pmean, const float* __restrict__ pmax,
                        float* __restrict__ gvec) {
    int t = threadIdx.x;
    float s = 0.f, m = -1e30f;
    for (int b = 0; b < 40; b++) { s += pmean[b*256 + t]; m = fmaxf(m, pmax[b*256 + t]); }
    gvec[t] = s * (1.f / (float)NN);
    gvec[256 + t] = m;
}

// ---------------- final FC (+relu) and LN ----------------
__global__ void k_fc(const float* __restrict__ gvec, const float* __restrict__ Wfc,
                     const float* __restrict__ bfc, float* __restrict__ fcp) {
    int c = blockIdx.x * 128 + threadIdx.x;
    float acc = bfc[c];
    for (int i = 0; i < 512; i++) acc += gvec[i] * Wfc[i * LATD + c];
    fcp[c] = fmaxf(acc, 0.f);
}

__global__ void k_out(const float* __restrict__ fcp, const float* __restrict__ gf,
                      const float* __restrict__ bf, float* __restrict__ outp) {
    __shared__ float sm[16];
    int t = threadIdx.x;
    float v = fcp[t];
    float mu = block_reduce_sum1(v, sm) * (1.f / 1024.f);
    float dv = v - mu;
    float var = block_reduce_sum1(dv * dv, sm) * (1.f / 1024.f);
    float rstd = rsqrtf(var + 1e-5f);
    outp[t] = gf[t] * dv * rstd + bf[t];
}

// ---------------- launch ----------------
extern "C" void kernel_launch(void* const* d_in, const int* in_sizes, int n_in,
                              void* d_out, int out_size, void* d_ws, size_t ws_size,
                              hipStream_t stream) {
    const float* x      = (const float*)d_in[0];
    const float* ea     = (const float*)d_in[1];
    const float* W1     = (const float*)d_in[2];
    const float* a_src1 = (const float*)d_in[3];
    const float* a_dst1 = (const float*)d_in[4];
    const float* We1    = (const float*)d_in[5];
    const float* a_e1   = (const float*)d_in[6];
    const float* b1     = (const float*)d_in[7];
    const float* g1     = (const float*)d_in[8];
    const float* be1    = (const float*)d_in[9];
    const float* W2     = (const float*)d_in[10];
    const float* a_src2 = (const float*)d_in[11];
    const float* a_dst2 = (const float*)d_in[12];
    const float* We2    = (const float*)d_in[13];
    const float* a_e2   = (const float*)d_in[14];
    const float* b2     = (const float*)d_in[15];
    const float* g2     = (const float*)d_in[16];
    const float* be2    = (const float*)d_in[17];
    const float* Wfc    = (const float*)d_in[18];
    const float* bfc    = (const float*)d_in[19];
    const float* gf     = (const float*)d_in[20];
    const float* bf     = (const float*)d_in[21];
    const int*   ei     = (const int*)d_in[22];
    float* outp = (float*)d_out;

    char* p = (char*)d_ws;
    auto alloc = [&](size_t bytes) -> char* {
        char* r = p;
        p += (bytes + 255) & ~(size_t)255;
        return r;
    };
    // zero zone (one memset): cnt, lea3, fill1
    float* cnt     = (float*)alloc((size_t)NN * 4);
    float* lea3    = (float*)alloc((size_t)NN * 3 * 4);
    int*   fill1   = (int*)  alloc((size_t)NN * 4);
    size_t zbytes  = (size_t)((char*)fill1 + (size_t)NN*4 - (char*)cnt);
    float* loop_ea = (float*)alloc((size_t)NN * 3 * 4);
    float* prm     = (float*)alloc(256 * 4);
    float* al1     = (float*)alloc((size_t)NN * 8 * 4);
    float* al2     = (float*)alloc((size_t)NN * 2 * 4);
    int*   offs    = (int*)  alloc((size_t)(NN + 1) * 4);
    int*   eslot   = (int*)  alloc((size_t)NEP * 4);
    int*   csrs    = (int*)  alloc((size_t)NEP * 4);
    float* cex1    = (float*)alloc((size_t)NEP * 4 * 4);
    float* cex2    = (float*)alloc((size_t)NEP * 4);
    __hip_bfloat16* h1  = (__hip_bfloat16*)alloc((size_t)NN * HCD * 2);
    __hip_bfloat16* h1b = (__hip_bfloat16*)alloc((size_t)MPAD * HCD * 2);
    __hip_bfloat16* w2t = (__hip_bfloat16*)alloc((size_t)HIDD * HCD * 2);
    __hip_bfloat16* h2b = (__hip_bfloat16*)alloc((size_t)NN * HIDD * 2);
    float* h2ln    = (float*)alloc((size_t)NN * HIDD * 4);
    float* pmean   = (float*)alloc(40 * 256 * 4);
    float* pmax    = (float*)alloc(40 * 256 * 4);
    float* gvec    = (float*)alloc(512 * 4);
    float* fcp     = (float*)alloc(1024 * 4);

    hipMemsetAsync(cnt, 0, zbytes, stream);

    k_prep<<<1, 256, 0, stream>>>(W1, a_src1, a_dst1, We1, a_e1, We2, a_e2, prm);
    k_w2t<<<dim3(16, 4), 256, 0, stream>>>(W2, w2t);
    k_deg<<<(NE + 255) / 256, 256, 0, stream>>>(ei, ea, cnt, lea3);
    k_loopea<<<(NN + 255) / 256, 256, 0, stream>>>(cnt, lea3, loop_ea);
    k_scan<<<1, 1024, 0, stream>>>(cnt, offs);
    k_gemm1<<<dim3(NN / 8, 4), 256, 0, stream>>>(x, W1, h1);
    k_al1<<<(NN + 255) / 256, 256, 0, stream>>>(x, prm, al1);
    k_edge1<<<(NEP + 255) / 256, 256, 0, stream>>>(ei, ea, loop_ea, al1, prm, offs,
                                                   fill1, eslot, csrs, cex1);
    k_agg1<<<NN / 4, 256, 0, stream>>>(offs, csrs, cex1, h1, b1, g1, be1, h1b);
    k_gemm2m<<<313, 256, 0, stream>>>(h1b, w2t, h2b);
    k_al2<<<NN / 4, 256, 0, stream>>>(h2b, a_src2, a_dst2, al2);
    k_edge2<<<(NEP + 255) / 256, 256, 0, stream>>>(ei, ea, loop_ea, al2, prm, eslot, cex2);
    k_agg2<<<NN / 4, 256, 0, stream>>>(offs, csrs, cex2, h2b, b2, g2, be2, h2ln);
    k_pool<<<40, 256, 0, stream>>>(h2ln, pmean, pmax);
    k_pool2<<<1, 256, 0, stream>>>(pmean, pmax, gvec);
    k_fc<<<8, 128, 0, stream>>>(gvec, Wfc, bfc, fcp);
    k_out<<<1, 1024, 0, stream>>>(fcp, gf, bf, outp);
}